// Round 8
// baseline (242.737 us; speedup 1.0000x reference)
//
#include <hip/hip_runtime.h>

typedef __attribute__((ext_vector_type(8))) short bf16x8;
typedef __attribute__((ext_vector_type(4))) short s16x4;
typedef __attribute__((ext_vector_type(4))) float f32x4;
typedef __attribute__((ext_vector_type(4))) unsigned int u32x4;
typedef unsigned short u16;
typedef unsigned int u32;

#define P_TOT 32768
#define C_IN  256
// 0.125 (dh^-0.5) * log2(e): folded into q so softmax is exp2(s - m)
#define QSCALE 0.18033688f

__device__ __forceinline__ u16 f2bf(float f) {
  u32 u = __builtin_bit_cast(u32, f);
  u = (u + 0x7fffu + ((u >> 16) & 1u)) >> 16;
  return (u16)u;
}

#define GLOAD_LDS(gsrc, ldst)                                                  \
  __builtin_amdgcn_global_load_lds(                                            \
      (const __attribute__((address_space(1))) void*)(gsrc),                   \
      (__attribute__((address_space(3))) void*)(ldst), 16, 0, 0)

// ---------------- Kernel 1: transpose x [c][p] fp32 -> xT [p][c] bf16 ----------------
__global__ __launch_bounds__(256) void k_transpose(const float* __restrict__ x,
                                                   u16* __restrict__ xT) {
  __shared__ __align__(16) u16 tile[64][66];
  const int t = threadIdx.x;
  const int p0 = blockIdx.x * 64, c0 = blockIdx.y * 64;
  {
    const int cl = t >> 4, pl4 = (t & 15) * 4;
    #pragma unroll
    for (int r = 0; r < 4; ++r) {
      const int c = c0 + cl + r * 16;
      f32x4 v = *(const f32x4*)(x + (size_t)c * P_TOT + p0 + pl4);
      #pragma unroll
      for (int j = 0; j < 4; ++j) tile[cl + r * 16][pl4 + j] = f2bf(v[j]);
    }
  }
  __syncthreads();
  {
    const int pl = t >> 4, cl4 = (t & 15) * 4;
    #pragma unroll
    for (int r = 0; r < 4; ++r) {
      const int p = p0 + pl + r * 16;
      s16x4 o;
      #pragma unroll
      for (int j = 0; j < 4; ++j) o[j] = (short)tile[cl4 + j][pl + r * 16];
      *(s16x4*)(xT + (size_t)p * C_IN + c0 + cl4) = o;
    }
  }
}

// ---------------- Kernel 2: convert weights to bf16 ----------------
__global__ __launch_bounds__(256) void k_wconv(const float* __restrict__ wq,
                                               const float* __restrict__ wkv,
                                               const float* __restrict__ wo,
                                               u16* __restrict__ Wb, u16* __restrict__ wob) {
  const int i = blockIdx.x * 256 + threadIdx.x;
  if (i < 393216) {
    float v = (i < 131072) ? wq[i] : wkv[i - 131072];
    Wb[i] = f2bf(v);
  } else {
    const int j = i - 393216;
    wob[j] = f2bf(wo[j]);
  }
}

// ---------------- Kernel 3: QKV projection GEMM (m97 structure) ----------------
__global__ __launch_bounds__(256, 2) void k_qkv(const u16* __restrict__ xT,
                                                const u16* __restrict__ Wb,
                                                u16* __restrict__ qw, u16* __restrict__ kw,
                                                u16* __restrict__ vt) {
  __shared__ __align__(16) u16 As[128 * 64];
  __shared__ __align__(16) u16 Bs[128 * 64];
  const int t = threadIdx.x, lane = t & 63, wv = t >> 6;
  const int c = lane & 15, g = lane >> 4;
  const int wr = wv >> 1, wc = wv & 1;
  const int p0 = blockIdx.x * 128, o0 = blockIdx.y * 128;
  const int srow = lane >> 3, scol = (lane & 7) * 8;
  f32x4 acc[4][4];
  #pragma unroll
  for (int m = 0; m < 4; ++m)
    #pragma unroll
    for (int n = 0; n < 4; ++n) acc[m][n] = (f32x4){0.f, 0.f, 0.f, 0.f};

  for (int kt = 0; kt < 4; ++kt) {
    const int k0 = kt * 64;
    #pragma unroll
    for (int i = 0; i < 4; ++i) {
      const int ch = wv * 4 + i;
      GLOAD_LDS(xT + (size_t)(p0 + ch * 8 + srow) * C_IN + k0 + scol, &As[ch * 512]);
      GLOAD_LDS(Wb + (size_t)(o0 + ch * 8 + srow) * C_IN + k0 + scol, &Bs[ch * 512]);
    }
    __syncthreads();
    #pragma unroll
    for (int kk = 0; kk < 2; ++kk) {
      bf16x8 a[4], b[4];
      #pragma unroll
      for (int m = 0; m < 4; ++m)
        a[m] = *(const bf16x8*)&As[(wr * 64 + m * 16 + c) * 64 + kk * 32 + g * 8];
      #pragma unroll
      for (int n = 0; n < 4; ++n)
        b[n] = *(const bf16x8*)&Bs[(wc * 64 + n * 16 + c) * 64 + kk * 32 + g * 8];
      #pragma unroll
      for (int m = 0; m < 4; ++m)
        #pragma unroll
        for (int n = 0; n < 4; ++n)
          acc[m][n] = __builtin_amdgcn_mfma_f32_16x16x32_bf16(a[m], b[n], acc[m][n], 0, 0, 0);
    }
    __syncthreads();
  }

  const int f = p0 >> 14, h = (p0 >> 7) & 127;
  const int tokb = f * 256 + (h & 15) * 16 + g * 4;
  const int winrow = (h >> 4) * 8;
  const int head = (blockIdx.y * 2 + wc) & 7;
  const int tsel = blockIdx.y >> 2;
  #pragma unroll
  for (int m = 0; m < 4; ++m) {
    const int win = winrow + wr * 4 + m;
    const size_t hw = (size_t)head * 64 + win;
    #pragma unroll
    for (int n = 0; n < 4; ++n) {
      const int d = n * 16 + c;
      if (tsel == 2) {
        s16x4 pk;
        #pragma unroll
        for (int r = 0; r < 4; ++r) pk[r] = (short)f2bf(acc[m][n][r]);
        *(s16x4*)(vt + (hw * 64 + d) * 512 + tokb) = pk;
      } else {
        u16* dst = (tsel == 0 ? qw : kw) + (hw * 512 + tokb) * 64 + d;
        const float sc = (tsel == 0) ? QSCALE : 1.0f;
        #pragma unroll
        for (int r = 0; r < 4; ++r) dst[(size_t)r * 64] = f2bf(acc[m][n][r] * sc);
      }
    }
  }
}

// ---------------- Kernel 4: windowed attention (swapped QK^T, reg-built P frags) ----------------
// R7 verified skeleton; PV now builds the A-frag in registers with f2bf packing
// (no pbuf LDS round-trip). Custom k-convention sigma(g,j) = {g*4+j | 16+g*4+(j-4)}
// applied to BOTH A (P values) and B (V reads) -> consistent k coverage.
#define KPAD 72   // 144 B = 16B*9  -> balanced bank groups
#define VPAD 264  // 528 B = 16B*33 -> balanced
__global__ __launch_bounds__(512, 2) void k_attn(const u16* __restrict__ qw,
                                                 const u16* __restrict__ kw,
                                                 const u16* __restrict__ vt,
                                                 u16* __restrict__ ao) {
  __shared__ __align__(16) u16 kv[256 * KPAD];
  const int t = threadIdx.x;
  const int lane = t & 63, wv = t >> 6;
  const int c = lane & 15, g = lane >> 4;
  const int win = blockIdx.x, head = blockIdx.y, qq = blockIdx.z;
  const size_t base = ((size_t)head * 64 + win) * 512 * 64;
  const int xw = win >> 3, yw = win & 7;
  const int qrow = qq * 128 + wv * 16;

  // Q fragments (B-operand of swapped mfma)
  const u16* qp = qw + base + (size_t)(qrow + c) * 64 + g * 8;
  bf16x8 q0 = *(const bf16x8*)(qp);
  bf16x8 q1 = *(const bf16x8*)(qp + 32);

  f32x4 s[32];

  // --- S^T pass: two K phases of 256 tokens ---
  #pragma unroll
  for (int kh = 0; kh < 2; ++kh) {
    if (kh) __syncthreads();
    {
      const u16* src = kw + base + (size_t)kh * 256 * 64;
      #pragma unroll
      for (int i = 0; i < 4; ++i) {
        const int chunk = i * 512 + t;
        const int row = chunk >> 3, col8 = chunk & 7;
        *(bf16x8*)&kv[row * KPAD + col8 * 8] = *(const bf16x8*)(src + chunk * 8);
      }
    }
    __syncthreads();
    #pragma unroll
    for (int jt = 0; jt < 16; ++jt) {
      const u16* kp = &kv[(jt * 16 + c) * KPAD + g * 8];
      bf16x8 k0 = *(const bf16x8*)(kp);
      bf16x8 k1 = *(const bf16x8*)(kp + 32);
      // swapped: A=K, B=Q -> lane (c,g) holds S[qrow c][toks jt*16+g*4+0..3]
      f32x4 t0 = __builtin_amdgcn_mfma_f32_16x16x32_bf16(k0, q0, (f32x4){0.f,0.f,0.f,0.f}, 0, 0, 0);
      s[kh * 16 + jt] = __builtin_amdgcn_mfma_f32_16x16x32_bf16(k1, q1, t0, 0, 0, 0);
    }
  }

  // --- softmax max: lane-local (q-row = c) + combine the 4 g-groups ---
  float m = -1e30f;
  #pragma unroll
  for (int jt = 0; jt < 32; ++jt)
    #pragma unroll
    for (int r = 0; r < 4; ++r) m = fmaxf(m, s[jt][r]);
  m = fmaxf(m, __shfl_xor(m, 16, 64));
  m = fmaxf(m, __shfl_xor(m, 32, 64));

  float rs = 0.f;
  f32x4 out4[4];
  #pragma unroll
  for (int dt = 0; dt < 4; ++dt) out4[dt] = (f32x4){0.f, 0.f, 0.f, 0.f};

  // --- PV: two V phases of 256 tokens ---
  #pragma unroll
  for (int vh = 0; vh < 2; ++vh) {
    __syncthreads();
    {
      const u16* src = vt + base + (size_t)vh * 256;
      #pragma unroll
      for (int i = 0; i < 4; ++i) {
        const int chunk = i * 512 + t;
        const int row = chunk >> 5, col8 = chunk & 31;
        *(bf16x8*)&kv[row * VPAD + col8 * 8] = *(const bf16x8*)(src + (size_t)row * 512 + col8 * 8);
      }
    }
    __syncthreads();
    #pragma unroll
    for (int jp = 0; jp < 8; ++jp) {
      const int jt0 = vh * 16 + jp * 2;
      f32x4 pa, pb;
      #pragma unroll
      for (int r = 0; r < 4; ++r) {
        pa[r] = __builtin_amdgcn_exp2f(s[jt0][r]     - m);  // toks jp*32+g*4+r
        pb[r] = __builtin_amdgcn_exp2f(s[jt0 + 1][r] - m);  // toks jp*32+16+g*4+r
        rs += pa[r] + pb[r];
      }
      // A-frag via explicit f2bf packing (word = lo | hi<<16), custom convention:
      // slots 0..3 -> toks jp*32+g*4+(0..3); slots 4..7 -> toks jp*32+16+g*4+(0..3)
      u32x4 aw = { (u32)f2bf(pa[0]) | ((u32)f2bf(pa[1]) << 16),
                   (u32)f2bf(pa[2]) | ((u32)f2bf(pa[3]) << 16),
                   (u32)f2bf(pb[0]) | ((u32)f2bf(pb[1]) << 16),
                   (u32)f2bf(pb[2]) | ((u32)f2bf(pb[3]) << 16) };
      const bf16x8 af = __builtin_bit_cast(bf16x8, aw);
      #pragma unroll
      for (int dt = 0; dt < 4; ++dt) {
        // V B-frag with the SAME convention: two b64 reads at +0 and +16 toks
        const u16* vp = &kv[(dt * 16 + c) * VPAD + jp * 32 + g * 4];
        s16x4 vlo = *(const s16x4*)(vp);        // toks jp*32 + g*4 + 0..3
        s16x4 vhi = *(const s16x4*)(vp + 16);   // toks jp*32 + 16 + g*4 + 0..3
        bf16x8 vf;
        vf[0] = vlo[0]; vf[1] = vlo[1]; vf[2] = vlo[2]; vf[3] = vlo[3];
        vf[4] = vhi[0]; vf[5] = vhi[1]; vf[6] = vhi[2]; vf[7] = vhi[3];
        out4[dt] = __builtin_amdgcn_mfma_f32_16x16x32_bf16(af, vf, out4[dt], 0, 0, 0);
      }
    }
  }

  // --- row sum combine + normalize + store (identical to R7) ---
  rs += __shfl_xor(rs, 16, 64);
  rs += __shfl_xor(rs, 32, 64);
  const float inv = 1.0f / rs;
  #pragma unroll
  for (int r = 0; r < 4; ++r) {
    const int row = g * 4 + r;
    const float ir = __shfl(inv, row, 64);
    const int tok = qrow + row;
    const int f = tok >> 8, w1 = (tok >> 4) & 15, w2 = tok & 15;
    const size_t p = (size_t)f * 16384 + (size_t)(xw * 16 + w1) * 128 + yw * 16 + w2;
    #pragma unroll
    for (int dt = 0; dt < 4; ++dt)
      ao[p * 512 + head * 64 + dt * 16 + c] = f2bf(out4[dt][r] * ir);
  }
}

// ---------------- Kernel 5: output projection GEMM (m97 structure) ----------------
__global__ __launch_bounds__(256, 2) void k_oproj(const u16* __restrict__ ao,
                                                  const u16* __restrict__ wob,
                                                  const float* __restrict__ bo,
                                                  float* __restrict__ out) {
  __shared__ __align__(16) u16 As[128 * 64];
  __shared__ __align__(16) u16 Bs[128 * 64];
  const int t = threadIdx.x, lane = t & 63, wv = t >> 6;
  const int c = lane & 15, g = lane >> 4;
  const int wr = wv >> 1, wc = wv & 1;
  const int p0 = blockIdx.x * 128, o0 = blockIdx.y * 128;
  const int srow = lane >> 3, scol = (lane & 7) * 8;
  f32x4 acc[4][4];
  #pragma unroll
  for (int m = 0; m < 4; ++m)
    #pragma unroll
    for (int n = 0; n < 4; ++n) acc[m][n] = (f32x4){0.f, 0.f, 0.f, 0.f};

  for (int kt = 0; kt < 8; ++kt) {
    const int k0 = kt * 64;
    #pragma unroll
    for (int i = 0; i < 4; ++i) {
      const int ch = wv * 4 + i;
      GLOAD_LDS(ao + (size_t)(p0 + ch * 8 + srow) * 512 + k0 + scol, &As[ch * 512]);
      GLOAD_LDS(wob + (size_t)(o0 + ch * 8 + srow) * 512 + k0 + scol, &Bs[ch * 512]);
    }
    __syncthreads();
    #pragma unroll
    for (int kk = 0; kk < 2; ++kk) {
      bf16x8 a[4], b[4];
      #pragma unroll
      for (int m = 0; m < 4; ++m)
        a[m] = *(const bf16x8*)&As[(wr * 64 + m * 16 + c) * 64 + kk * 32 + g * 8];
      #pragma unroll
      for (int n = 0; n < 4; ++n)
        b[n] = *(const bf16x8*)&Bs[(wc * 64 + n * 16 + c) * 64 + kk * 32 + g * 8];
      #pragma unroll
      for (int m = 0; m < 4; ++m)
        #pragma unroll
        for (int n = 0; n < 4; ++n)
          acc[m][n] = __builtin_amdgcn_mfma_f32_16x16x32_bf16(a[m], b[n], acc[m][n], 0, 0, 0);
    }
    __syncthreads();
  }

  #pragma unroll
  for (int n = 0; n < 4; ++n) {
    const int o2 = o0 + wc * 64 + n * 16 + c;
    const float bias = bo[o2];
    #pragma unroll
    for (int m = 0; m < 4; ++m) {
      f32x4 v;
      #pragma unroll
      for (int r = 0; r < 4; ++r) v[r] = acc[m][n][r] + bias;
      *(f32x4*)(out + (size_t)o2 * P_TOT + p0 + wr * 64 + m * 16 + g * 4) = v;
    }
  }
}

extern "C" void kernel_launch(void* const* d_in, const int* in_sizes, int n_in,
                              void* d_out, int out_size, void* d_ws, size_t ws_size,
                              hipStream_t stream) {
  const float* x   = (const float*)d_in[0];
  const float* wq  = (const float*)d_in[1];
  const float* wkv = (const float*)d_in[2];
  const float* wo  = (const float*)d_in[3];
  const float* bo  = (const float*)d_in[4];
  float* out = (float*)d_out;

  u16* ws  = (u16*)d_ws;
  u16* xT  = ws;                     // 32768*256      =  8,388,608
  u16* Wb  = xT + 8388608;           // 1536*256       =    393,216
  u16* wob = Wb + 393216;            // 256*512        =    131,072
  u16* qw  = wob + 131072;           // 8*64*512*64    = 16,777,216
  u16* kw  = qw + 16777216;
  u16* vt  = kw + 16777216;          // [head][win][64][512]
  u16* ao  = vt + 16777216;          // [p][512]

  dim3 blk(256);
  k_transpose<<<dim3(512, 4), blk, 0, stream>>>(x, xT);
  k_wconv<<<dim3(2048), blk, 0, stream>>>(wq, wkv, wo, Wb, wob);
  k_qkv<<<dim3(256, 12), blk, 0, stream>>>(xT, Wb, qw, kw, vt);
  k_attn<<<dim3(64, 8, 4), dim3(512), 0, stream>>>(qw, kw, vt, ao);
  k_oproj<<<dim3(256, 2), blk, 0, stream>>>(ao, wob, bo, out);
}

// Round 9
// 239.756 us; speedup vs baseline: 1.0124x; 1.0124x over previous
//
#include <hip/hip_runtime.h>

typedef __attribute__((ext_vector_type(8))) short bf16x8;
typedef __attribute__((ext_vector_type(4))) short s16x4;
typedef __attribute__((ext_vector_type(4))) float f32x4;
typedef __attribute__((ext_vector_type(4))) unsigned int u32x4;
typedef unsigned short u16;
typedef unsigned int u32;

#define P_TOT 32768
#define C_IN  256
// 0.125 (dh^-0.5) * log2(e): folded into q so softmax is exp2(s - m)
#define QSCALE 0.18033688f

__device__ __forceinline__ u16 f2bf(float f) {
  u32 u = __builtin_bit_cast(u32, f);
  u = (u + 0x7fffu + ((u >> 16) & 1u)) >> 16;
  return (u16)u;
}

#define GLOAD_LDS(gsrc, ldst)                                                  \
  __builtin_amdgcn_global_load_lds(                                            \
      (const __attribute__((address_space(1))) void*)(gsrc),                   \
      (__attribute__((address_space(3))) void*)(ldst), 16, 0, 0)

// ---------------- Kernel 1: transpose x [c][p] fp32 -> xT [p][c] bf16 ----------------
__global__ __launch_bounds__(256) void k_transpose(const float* __restrict__ x,
                                                   u16* __restrict__ xT) {
  __shared__ __align__(16) u16 tile[64][66];
  const int t = threadIdx.x;
  const int p0 = blockIdx.x * 64, c0 = blockIdx.y * 64;
  {
    const int cl = t >> 4, pl4 = (t & 15) * 4;
    #pragma unroll
    for (int r = 0; r < 4; ++r) {
      const int c = c0 + cl + r * 16;
      f32x4 v = *(const f32x4*)(x + (size_t)c * P_TOT + p0 + pl4);
      #pragma unroll
      for (int j = 0; j < 4; ++j) tile[cl + r * 16][pl4 + j] = f2bf(v[j]);
    }
  }
  __syncthreads();
  {
    const int pl = t >> 4, cl4 = (t & 15) * 4;
    #pragma unroll
    for (int r = 0; r < 4; ++r) {
      const int p = p0 + pl + r * 16;
      s16x4 o;
      #pragma unroll
      for (int j = 0; j < 4; ++j) o[j] = (short)tile[cl4 + j][pl + r * 16];
      *(s16x4*)(xT + (size_t)p * C_IN + c0 + cl4) = o;
    }
  }
}

// ---------------- Kernel 2: convert weights to bf16 ----------------
__global__ __launch_bounds__(256) void k_wconv(const float* __restrict__ wq,
                                               const float* __restrict__ wkv,
                                               const float* __restrict__ wo,
                                               u16* __restrict__ Wb, u16* __restrict__ wob) {
  const int i = blockIdx.x * 256 + threadIdx.x;
  if (i < 393216) {
    float v = (i < 131072) ? wq[i] : wkv[i - 131072];
    Wb[i] = f2bf(v);
  } else {
    const int j = i - 393216;
    wob[j] = f2bf(wo[j]);
  }
}

// ---------------- Kernel 3: QKV projection GEMM (m97 structure) ----------------
// vt is written in sigma-permuted token order: within each 32-token chunk,
// tok = 32J + 16h + 4g + r  ->  offset 32J + 8g + 4h + r, so k_attn's PV can
// read one b128 per (dt, jp) that matches the reg-built A-frag convention.
__global__ __launch_bounds__(256, 2) void k_qkv(const u16* __restrict__ xT,
                                                const u16* __restrict__ Wb,
                                                u16* __restrict__ qw, u16* __restrict__ kw,
                                                u16* __restrict__ vt) {
  __shared__ __align__(16) u16 As[128 * 64];
  __shared__ __align__(16) u16 Bs[128 * 64];
  const int t = threadIdx.x, lane = t & 63, wv = t >> 6;
  const int c = lane & 15, g = lane >> 4;
  const int wr = wv >> 1, wc = wv & 1;
  const int p0 = blockIdx.x * 128, o0 = blockIdx.y * 128;
  const int srow = lane >> 3, scol = (lane & 7) * 8;
  f32x4 acc[4][4];
  #pragma unroll
  for (int m = 0; m < 4; ++m)
    #pragma unroll
    for (int n = 0; n < 4; ++n) acc[m][n] = (f32x4){0.f, 0.f, 0.f, 0.f};

  for (int kt = 0; kt < 4; ++kt) {
    const int k0 = kt * 64;
    #pragma unroll
    for (int i = 0; i < 4; ++i) {
      const int ch = wv * 4 + i;
      GLOAD_LDS(xT + (size_t)(p0 + ch * 8 + srow) * C_IN + k0 + scol, &As[ch * 512]);
      GLOAD_LDS(Wb + (size_t)(o0 + ch * 8 + srow) * C_IN + k0 + scol, &Bs[ch * 512]);
    }
    __syncthreads();
    #pragma unroll
    for (int kk = 0; kk < 2; ++kk) {
      bf16x8 a[4], b[4];
      #pragma unroll
      for (int m = 0; m < 4; ++m)
        a[m] = *(const bf16x8*)&As[(wr * 64 + m * 16 + c) * 64 + kk * 32 + g * 8];
      #pragma unroll
      for (int n = 0; n < 4; ++n)
        b[n] = *(const bf16x8*)&Bs[(wc * 64 + n * 16 + c) * 64 + kk * 32 + g * 8];
      #pragma unroll
      for (int m = 0; m < 4; ++m)
        #pragma unroll
        for (int n = 0; n < 4; ++n)
          acc[m][n] = __builtin_amdgcn_mfma_f32_16x16x32_bf16(a[m], b[n], acc[m][n], 0, 0, 0);
    }
    __syncthreads();
  }

  const int f = p0 >> 14, h = (p0 >> 7) & 127;
  const int T = h & 15;
  const int tokb   = f * 256 + T * 16 + g * 4;                    // q/k layout
  const int tokb_v = f * 256 + (T >> 1) * 32 + (T & 1) * 4 + g * 8;  // sigma-permuted v
  const int winrow = (h >> 4) * 8;
  const int head = (blockIdx.y * 2 + wc) & 7;
  const int tsel = blockIdx.y >> 2;
  #pragma unroll
  for (int m = 0; m < 4; ++m) {
    const int win = winrow + wr * 4 + m;
    const size_t hw = (size_t)head * 64 + win;
    #pragma unroll
    for (int n = 0; n < 4; ++n) {
      const int d = n * 16 + c;
      if (tsel == 2) {
        s16x4 pk;
        #pragma unroll
        for (int r = 0; r < 4; ++r) pk[r] = (short)f2bf(acc[m][n][r]);
        *(s16x4*)(vt + (hw * 64 + d) * 512 + tokb_v) = pk;
      } else {
        u16* dst = (tsel == 0 ? qw : kw) + (hw * 512 + tokb) * 64 + d;
        const float sc = (tsel == 0) ? QSCALE : 1.0f;
        #pragma unroll
        for (int r = 0; r < 4; ++r) dst[(size_t)r * 64] = f2bf(acc[m][n][r] * sc);
      }
    }
  }
}

// ---------------- Kernel 4: windowed attention (swapped QK^T, reg-built P frags) ----------------
// R8 structure, but V reads are single ds_read_b128: vt's producer-side token
// permutation makes LDS offset jp*32+g*8 deliver toks {32jp+4g+r, 32jp+16+4g+r}
// (the sigma convention) contiguously. PV values bit-identical to R8.
#define KPAD 72   // 144 B = 16B*9  -> balanced bank groups
#define VPAD 264  // 528 B = 16B*33 -> balanced
__global__ __launch_bounds__(512, 2) void k_attn(const u16* __restrict__ qw,
                                                 const u16* __restrict__ kw,
                                                 const u16* __restrict__ vt,
                                                 u16* __restrict__ ao) {
  __shared__ __align__(16) u16 kv[256 * KPAD];
  const int t = threadIdx.x;
  const int lane = t & 63, wv = t >> 6;
  const int c = lane & 15, g = lane >> 4;
  const int win = blockIdx.x, head = blockIdx.y, qq = blockIdx.z;
  const size_t base = ((size_t)head * 64 + win) * 512 * 64;
  const int xw = win >> 3, yw = win & 7;
  const int qrow = qq * 128 + wv * 16;

  // Q fragments (B-operand of swapped mfma)
  const u16* qp = qw + base + (size_t)(qrow + c) * 64 + g * 8;
  bf16x8 q0 = *(const bf16x8*)(qp);
  bf16x8 q1 = *(const bf16x8*)(qp + 32);

  f32x4 s[32];

  // --- S^T pass: two K phases of 256 tokens ---
  #pragma unroll
  for (int kh = 0; kh < 2; ++kh) {
    if (kh) __syncthreads();
    {
      const u16* src = kw + base + (size_t)kh * 256 * 64;
      #pragma unroll
      for (int i = 0; i < 4; ++i) {
        const int chunk = i * 512 + t;
        const int row = chunk >> 3, col8 = chunk & 7;
        *(bf16x8*)&kv[row * KPAD + col8 * 8] = *(const bf16x8*)(src + chunk * 8);
      }
    }
    __syncthreads();
    #pragma unroll
    for (int jt = 0; jt < 16; ++jt) {
      const u16* kp = &kv[(jt * 16 + c) * KPAD + g * 8];
      bf16x8 k0 = *(const bf16x8*)(kp);
      bf16x8 k1 = *(const bf16x8*)(kp + 32);
      // swapped: A=K, B=Q -> lane (c,g) holds S[qrow c][toks jt*16+g*4+0..3]
      f32x4 t0 = __builtin_amdgcn_mfma_f32_16x16x32_bf16(k0, q0, (f32x4){0.f,0.f,0.f,0.f}, 0, 0, 0);
      s[kh * 16 + jt] = __builtin_amdgcn_mfma_f32_16x16x32_bf16(k1, q1, t0, 0, 0, 0);
    }
  }

  // --- softmax max: lane-local (q-row = c) + combine the 4 g-groups ---
  float m = -1e30f;
  #pragma unroll
  for (int jt = 0; jt < 32; ++jt)
    #pragma unroll
    for (int r = 0; r < 4; ++r) m = fmaxf(m, s[jt][r]);
  m = fmaxf(m, __shfl_xor(m, 16, 64));
  m = fmaxf(m, __shfl_xor(m, 32, 64));

  float rs = 0.f;
  f32x4 out4[4];
  #pragma unroll
  for (int dt = 0; dt < 4; ++dt) out4[dt] = (f32x4){0.f, 0.f, 0.f, 0.f};

  // --- PV: two V phases of 256 tokens ---
  #pragma unroll
  for (int vh = 0; vh < 2; ++vh) {
    __syncthreads();
    {
      const u16* src = vt + base + (size_t)vh * 256;
      #pragma unroll
      for (int i = 0; i < 4; ++i) {
        const int chunk = i * 512 + t;
        const int row = chunk >> 5, col8 = chunk & 31;
        *(bf16x8*)&kv[row * VPAD + col8 * 8] = *(const bf16x8*)(src + (size_t)row * 512 + col8 * 8);
      }
    }
    __syncthreads();
    #pragma unroll
    for (int jp = 0; jp < 8; ++jp) {
      const int jt0 = vh * 16 + jp * 2;
      f32x4 pa, pb;
      #pragma unroll
      for (int r = 0; r < 4; ++r) {
        pa[r] = __builtin_amdgcn_exp2f(s[jt0][r]     - m);  // toks jp*32+g*4+r
        pb[r] = __builtin_amdgcn_exp2f(s[jt0 + 1][r] - m);  // toks jp*32+16+g*4+r
        rs += pa[r] + pb[r];
      }
      // A-frag via explicit f2bf packing, sigma convention:
      // slots 0..3 -> toks jp*32+g*4+(0..3); slots 4..7 -> toks jp*32+16+g*4+(0..3)
      u32x4 aw = { (u32)f2bf(pa[0]) | ((u32)f2bf(pa[1]) << 16),
                   (u32)f2bf(pa[2]) | ((u32)f2bf(pa[3]) << 16),
                   (u32)f2bf(pb[0]) | ((u32)f2bf(pb[1]) << 16),
                   (u32)f2bf(pb[2]) | ((u32)f2bf(pb[3]) << 16) };
      const bf16x8 af = __builtin_bit_cast(bf16x8, aw);
      #pragma unroll
      for (int dt = 0; dt < 4; ++dt) {
        // single b128: permuted vt delivers the sigma token order here
        bf16x8 vf = *(const bf16x8*)&kv[(dt * 16 + c) * VPAD + jp * 32 + g * 8];
        out4[dt] = __builtin_amdgcn_mfma_f32_16x16x32_bf16(af, vf, out4[dt], 0, 0, 0);
      }
    }
  }

  // --- row sum combine + normalize + store ---
  rs += __shfl_xor(rs, 16, 64);
  rs += __shfl_xor(rs, 32, 64);
  const float inv = 1.0f / rs;
  #pragma unroll
  for (int r = 0; r < 4; ++r) {
    const int row = g * 4 + r;
    const float ir = __shfl(inv, row, 64);
    const int tok = qrow + row;
    const int f = tok >> 8, w1 = (tok >> 4) & 15, w2 = tok & 15;
    const size_t p = (size_t)f * 16384 + (size_t)(xw * 16 + w1) * 128 + yw * 16 + w2;
    #pragma unroll
    for (int dt = 0; dt < 4; ++dt)
      ao[p * 512 + head * 64 + dt * 16 + c] = f2bf(out4[dt][r] * ir);
  }
}

// ---------------- Kernel 5: output projection GEMM (m97 structure) ----------------
__global__ __launch_bounds__(256, 2) void k_oproj(const u16* __restrict__ ao,
                                                  const u16* __restrict__ wob,
                                                  const float* __restrict__ bo,
                                                  float* __restrict__ out) {
  __shared__ __align__(16) u16 As[128 * 64];
  __shared__ __align__(16) u16 Bs[128 * 64];
  const int t = threadIdx.x, lane = t & 63, wv = t >> 6;
  const int c = lane & 15, g = lane >> 4;
  const int wr = wv >> 1, wc = wv & 1;
  const int p0 = blockIdx.x * 128, o0 = blockIdx.y * 128;
  const int srow = lane >> 3, scol = (lane & 7) * 8;
  f32x4 acc[4][4];
  #pragma unroll
  for (int m = 0; m < 4; ++m)
    #pragma unroll
    for (int n = 0; n < 4; ++n) acc[m][n] = (f32x4){0.f, 0.f, 0.f, 0.f};

  for (int kt = 0; kt < 8; ++kt) {
    const int k0 = kt * 64;
    #pragma unroll
    for (int i = 0; i < 4; ++i) {
      const int ch = wv * 4 + i;
      GLOAD_LDS(ao + (size_t)(p0 + ch * 8 + srow) * 512 + k0 + scol, &As[ch * 512]);
      GLOAD_LDS(wob + (size_t)(o0 + ch * 8 + srow) * 512 + k0 + scol, &Bs[ch * 512]);
    }
    __syncthreads();
    #pragma unroll
    for (int kk = 0; kk < 2; ++kk) {
      bf16x8 a[4], b[4];
      #pragma unroll
      for (int m = 0; m < 4; ++m)
        a[m] = *(const bf16x8*)&As[(wr * 64 + m * 16 + c) * 64 + kk * 32 + g * 8];
      #pragma unroll
      for (int n = 0; n < 4; ++n)
        b[n] = *(const bf16x8*)&Bs[(wc * 64 + n * 16 + c) * 64 + kk * 32 + g * 8];
      #pragma unroll
      for (int m = 0; m < 4; ++m)
        #pragma unroll
        for (int n = 0; n < 4; ++n)
          acc[m][n] = __builtin_amdgcn_mfma_f32_16x16x32_bf16(a[m], b[n], acc[m][n], 0, 0, 0);
    }
    __syncthreads();
  }

  #pragma unroll
  for (int n = 0; n < 4; ++n) {
    const int o2 = o0 + wc * 64 + n * 16 + c;
    const float bias = bo[o2];
    #pragma unroll
    for (int m = 0; m < 4; ++m) {
      f32x4 v;
      #pragma unroll
      for (int r = 0; r < 4; ++r) v[r] = acc[m][n][r] + bias;
      *(f32x4*)(out + (size_t)o2 * P_TOT + p0 + wr * 64 + m * 16 + g * 4) = v;
    }
  }
}

extern "C" void kernel_launch(void* const* d_in, const int* in_sizes, int n_in,
                              void* d_out, int out_size, void* d_ws, size_t ws_size,
                              hipStream_t stream) {
  const float* x   = (const float*)d_in[0];
  const float* wq  = (const float*)d_in[1];
  const float* wkv = (const float*)d_in[2];
  const float* wo  = (const float*)d_in[3];
  const float* bo  = (const float*)d_in[4];
  float* out = (float*)d_out;

  u16* ws  = (u16*)d_ws;
  u16* xT  = ws;                     // 32768*256      =  8,388,608
  u16* Wb  = xT + 8388608;           // 1536*256       =    393,216
  u16* wob = Wb + 393216;            // 256*512        =    131,072
  u16* qw  = wob + 131072;           // 8*64*512*64    = 16,777,216
  u16* kw  = qw + 16777216;
  u16* vt  = kw + 16777216;          // [head][win][64][tok-permuted 512]
  u16* ao  = vt + 16777216;          // [p][512]

  dim3 blk(256);
  k_transpose<<<dim3(512, 4), blk, 0, stream>>>(x, xT);
  k_wconv<<<dim3(2048), blk, 0, stream>>>(wq, wkv, wo, Wb, wob);
  k_qkv<<<dim3(256, 12), blk, 0, stream>>>(xT, Wb, qw, kw, vt);
  k_attn<<<dim3(64, 8, 4), dim3(512), 0, stream>>>(qw, kw, vt, ao);
  k_oproj<<<dim3(256, 2), blk, 0, stream>>>(ao, wob, bo, out);
}